// Round 1
// 129.713 us; speedup vs baseline: 1.0145x; 1.0145x over previous
//
#include <hip/hip_runtime.h>
#include <math.h>
#include <stdint.h>

// Problem dims (fixed by setup_inputs)
#define B_N 256
#define C_N 1152
#define I_N 8
#define N_N 10
#define D_N 16

constexpr int C_PER    = 18;             // c's per route block
constexpr int C_CHUNKS = C_N / C_PER;    // 64
constexpr int STAGE_C  = 3;              // c's per W staging round (double-buffered)
constexpr int N_STAGES = 6;
constexpr int BLOCK    = 256;
// route grid = 64 x 16 = 1024 blocks = exactly 4 blocks/CU

typedef short v8s __attribute__((ext_vector_type(8)));
typedef float v4f __attribute__((ext_vector_type(4)));

// ---- LDS pool (bytes), route_pass ----
//   wbuf (short): 2 x [3c][10n][16d][8i] = 15360 @ 0      (DMA, linear, dbuf)
//   xs   (short): [18c][16b][8i]         =  4608 @ 15360  (DMA, linear)
//   vst  (float): [16b][164]             = 10496 @ 19968  (DMA, linear, padded rows)
//   cfl  (float): [3c][163]              =  1956 @ 30464
//   comb (float): [16b][164] ALIASES wbuf                 @ 0
constexpr int POOL_BYTES = 32432;   // -> 4 blocks/CU (129.7 KB of 160)

// ws layout (floats unless noted):
constexpr size_t VSTG_FL = 16 * 16 * 164;
constexpr size_t PS_FL   = (size_t)C_CHUNKS * B_N * 160;
constexpr size_t WB_SH   = (size_t)C_N * 1280;
constexpr size_t XT_SH   = (size_t)1024 * 2304;

#define GLD16(g, l)                                                         \
    __builtin_amdgcn_global_load_lds(                                       \
        (const uint32_t __attribute__((address_space(1)))*)(g),             \
        (uint32_t __attribute__((address_space(3)))*)(l), 16, 0, 0)

// RNE pack of 2 f32 -> 1 u32 of 2 bf16 (single instr; same rounding as the
// old manual bit-twiddle pack2, so results are bitwise identical)
__device__ __forceinline__ uint32_t cvtpk(float a, float b) {
    uint32_t r;
    asm("v_cvt_pk_bf16_f32 %0, %1, %2" : "=v"(r) : "v"(a), "v"(b));
    return r;
}
__device__ __forceinline__ float bf2f(short s) {
    return __uint_as_float(((uint32_t)(uint16_t)s) << 16);
}

// ---- K0: fused W and x conversion (one dispatch) ----
// blocks [0,144)   : W fp32 -> bf16, layout [c][n][16d*8i]
// blocks [144,1168): x fp32 -> bf16 per-route-block tiles [tile][18c][16b][8i]
__global__ __launch_bounds__(BLOCK)
void conv_all(const float* __restrict__ x, const float* __restrict__ W,
              short* __restrict__ Wb, short* __restrict__ xt)
{
    if (blockIdx.x < 144) {
        const int c0 = blockIdx.x * 8;
        const int cc = threadIdx.x >> 5;        // 8 c's per block
        const int k4 = threadIdx.x & 31;        // 32 float4 per (n,c)
        const float4* W4 = (const float4*)W;
        uint2* dst = (uint2*)Wb;
        for (int n = 0; n < N_N; ++n) {
            float4 v = W4[(size_t)n * 36864 + (size_t)(c0 + cc) * 32 + k4];
            dst[(((size_t)(c0 + cc) * 1280 + n * 128) >> 2) + k4] =
                make_uint2(cvtpk(v.x, v.y), cvtpk(v.z, v.w));
        }
    } else {
        const int tile  = blockIdx.x - 144;      // chunk*16 + btile
        const int chunk = tile >> 4;
        const int btile = tile & 15;
        const int c0    = chunk * C_PER;
        const int gb0   = btile * 16;
        const float4* x4 = (const float4*)x;
        uint2* dst = (uint2*)(xt + (size_t)tile * 2304);
        #pragma unroll
        for (int it = 0; it < 3; ++it) {
            int f = threadIdx.x + BLOCK * it;    // < 576 float4
            if (f < 576) {
                int b = f / 36, r = f - b * 36;  // r: 36 float4 per b (18c*8i)
                float4 v = x4[(size_t)(gb0 + b) * 2304 + c0 * 2 + r];
                int cp = r >> 1, i0 = (r & 1) * 4;
                dst[((cp * 128 + b * 8 + i0) >> 2)] =
                    make_uint2(cvtpk(v.x, v.y), cvtpk(v.z, v.w));
            }
        }
    }
}

// ---- route pass: pipelined W staging (double-buffered, counted waits) ----
// Per stage st: W[st+1] DMA is issued BEFORE sweep1(st) and waited only at the
// end-of-stage barrier, so its flight time hides under a full stage of compute.
// Raw s_barrier + manual s_waitcnt keep the DMA in flight across the mid
// (cfl-publish) barrier. The old z-step is folded into sweep2: each thread
// sums its own Z over 10 cfl entries (quad-broadcast LDS reads), removing
// 2 barriers/stage and the 96-thread serialization.
template <bool FIRST>
__global__ __launch_bounds__(BLOCK, 4)
void route_pass(const short* __restrict__ Wb, const short* __restrict__ xt,
                const float* __restrict__ vstG, float* __restrict__ p_s)
{
    __shared__ __align__(16) char pool[POOL_BYTES];
    short* wbuf = (short*)pool;                  // [2][3c*1280]
    short* xs   = (short*)(pool + 15360);
    float* vst  = (float*)(pool + 19968);
    float* cfl  = (float*)(pool + 30464);
    float* comb = (float*)pool;

    const int tid   = threadIdx.x;
    const int wv    = tid >> 6;
    const int lane  = tid & 63;
    const int b     = lane & 15;   // D-col / B-col; also A-row m (=d)
    const int quad  = lane >> 4;
    const int chunk = blockIdx.x;
    const int btile = blockIdx.y;
    const int gb0   = btile * 16;
    const int c0    = chunk * C_PER;

    // ---- prologue DMA: xs (288x16B), vst (656x16B), W0, W1 (480x16B each) ----
    {
        const char* src = (const char*)(xt + (size_t)(chunk * 16 + btile) * 2304);
        #pragma unroll
        for (int it = 0; it < 2; ++it) {
            int f = tid + BLOCK * it;
            if (f < 288) GLD16(src + f * 16, (char*)xs + f * 16);
        }
    }
    asm volatile("" ::: "memory");
    if (!FIRST) {
        const char* src = (const char*)(vstG + (size_t)btile * 2624);
        #pragma unroll
        for (int it = 0; it < 3; ++it) {
            int f = tid + BLOCK * it;
            if (f < 656) GLD16(src + f * 16, (char*)vst + f * 16);
        }
    }
    asm volatile("" ::: "memory");
    // W0 then W1: each W stage is 480x16B -> exactly 2 GLD16 per wave (uniform)
    #pragma unroll
    for (int s0 = 0; s0 < 2; ++s0) {
        const char* src = (const char*)(Wb + (size_t)(c0 + s0 * STAGE_C) * 1280);
        char* dst = (char*)(wbuf + s0 * (STAGE_C * 1280));
        #pragma unroll
        for (int it = 0; it < 2; ++it) {
            int f = tid + BLOCK * it;
            if (f < 480) GLD16(src + f * 16, dst + f * 16);
        }
        asm volatile("" ::: "memory");
    }
    // wait until only the last 2 issued (W1) remain -> xs/vst/W0 landed,
    // regardless of per-wave issue counts for xs/vst (in-order vmcnt retire)
    asm volatile("s_waitcnt vmcnt(2)" ::: "memory");
    __builtin_amdgcn_s_barrier();

    const int ncnt = (wv < 2) ? 3 : 2;   // wave wv owns n = wv, wv+4, (wv+8)
    v4f sacc[3];
    sacc[0] = (v4f){0.f, 0.f, 0.f, 0.f};
    sacc[1] = (v4f){0.f, 0.f, 0.f, 0.f};
    sacc[2] = (v4f){0.f, 0.f, 0.f, 0.f};

    for (int st = 0; st < N_STAGES; ++st) {
        const short* Ws = wbuf + (st & 1) * (STAGE_C * 1280);

        // issue W[st+1] DMA into the buffer last read at stage st-1
        // (st=0's W1 was issued in the prologue)
        if (st >= 1 && st < N_STAGES - 1) {
            const char* src =
                (const char*)(Wb + (size_t)(c0 + (st + 1) * STAGE_C) * 1280);
            char* dst = (char*)(wbuf + ((st + 1) & 1) * (STAGE_C * 1280));
            #pragma unroll
            for (int it = 0; it < 2; ++it) {
                int f = tid + BLOCK * it;
                if (f < 480) GLD16(src + f * 16, dst + f * 16);
            }
            asm volatile("" ::: "memory");
        }

        if (!FIRST) {
            // ---- sweep1: 30 independent (c,n) chains over 4 waves (8/8/7/7) ----
            #pragma unroll
            for (int k = 0; k < 8; ++k) {
                const int idx = wv + 4 * k;
                if (idx < 30) {
                    const int c = idx / 10;
                    const int n = idx - c * 10;
                    v8s wa = {0, 0, 0, 0, 0, 0, 0, 0};
                    if (quad == 0)
                        wa = *(const v8s*)(Ws + c * 1280 + n * 128 + b * 8);
                    const v8s xb =
                        *(const v8s*)(xs + (st * STAGE_C + c) * 128 + b * 8);
                    v4f u = __builtin_amdgcn_mfma_f32_16x16x32_bf16(
                        wa, xb, (v4f){0.f, 0.f, 0.f, 0.f}, 0, 0, 0);
                    const float4 v4 =
                        *(const float4*)(vst + b * 164 + n * 16 + quad * 4);
                    float l = u[0] * v4.x + u[1] * v4.y + u[2] * v4.z + u[3] * v4.w;
                    l += __shfl_xor(l, 16);
                    l += __shfl_xor(l, 32);
                    const float e1 = __expf(l);   // |l| <~ 3: no max-sub needed
                    if (quad == 0) cfl[c * 163 + n * 16 + b] = e1;
                }
            }
            // publish cfl; W[st+1] DMA stays in flight (no vmcnt drain here)
            asm volatile("s_waitcnt lgkmcnt(0)" ::: "memory");
            __builtin_amdgcn_s_barrier();
        }

        // ---- sweep2: K=32 packs 3 c's (quad=c, quad3 zero-padded via wa=0) ----
        {
            const bool valid = (quad < STAGE_C);
            const int  cl    = valid ? quad : 0;
            const v8s xq =
                *(const v8s*)(xs + (st * STAGE_C + cl) * 128 + b * 8);
            float xf[8];
            #pragma unroll
            for (int j = 0; j < 8; ++j) xf[j] = bf2f(xq[j]);

            if (FIRST) {
                union { v8s s; uint32_t u[4]; } zu;
                zu.u[0] = cvtpk(0.1f * xf[0], 0.1f * xf[1]);
                zu.u[1] = cvtpk(0.1f * xf[2], 0.1f * xf[3]);
                zu.u[2] = cvtpk(0.1f * xf[4], 0.1f * xf[5]);
                zu.u[3] = cvtpk(0.1f * xf[6], 0.1f * xf[7]);
                #pragma unroll
                for (int jj = 0; jj < 3; ++jj) {
                    if (jj < ncnt) {
                        const int n = wv + 4 * jj;
                        v8s wa = {0, 0, 0, 0, 0, 0, 0, 0};
                        if (valid)
                            wa = *(const v8s*)(Ws + cl * 1280 + n * 128 + b * 8);
                        sacc[jj] = __builtin_amdgcn_mfma_f32_16x16x32_bf16(
                            wa, zu.s, sacc[jj], 0, 0, 0);
                    }
                }
            } else {
                // per-thread Z (folded z-step): 10 quad-broadcast cfl reads
                float Z = 0.f;
                #pragma unroll
                for (int n = 0; n < N_N; ++n) Z += cfl[cl * 163 + n * 16 + b];
                const float rzv = __builtin_amdgcn_rcpf(Z);
                #pragma unroll
                for (int jj = 0; jj < 3; ++jj) {
                    if (jj < ncnt) {
                        const int n = wv + 4 * jj;
                        const float cv = cfl[cl * 163 + n * 16 + b] * rzv;
                        union { v8s s; uint32_t u[4]; } zu;
                        zu.u[0] = cvtpk(cv * xf[0], cv * xf[1]);
                        zu.u[1] = cvtpk(cv * xf[2], cv * xf[3]);
                        zu.u[2] = cvtpk(cv * xf[4], cv * xf[5]);
                        zu.u[3] = cvtpk(cv * xf[6], cv * xf[7]);
                        v8s wa = {0, 0, 0, 0, 0, 0, 0, 0};
                        if (valid)
                            wa = *(const v8s*)(Ws + cl * 1280 + n * 128 + b * 8);
                        sacc[jj] = __builtin_amdgcn_mfma_f32_16x16x32_bf16(
                            wa, zu.s, sacc[jj], 0, 0, 0);
                    }
                }
            }
        }

        // end of stage: W[st+1] has had a full stage of compute to land ->
        // this vmcnt(0) is pre-satisfied in steady state
        asm volatile("s_waitcnt vmcnt(0) lgkmcnt(0)" ::: "memory");
        __builtin_amdgcn_s_barrier();
    }

    // loop-end barrier already synced all Ws/xs/cfl readers -> comb alias safe
    #pragma unroll
    for (int jj = 0; jj < 3; ++jj) {
        if (jj < ncnt) {
            const int n = wv + 4 * jj;
            #pragma unroll
            for (int r = 0; r < 4; ++r)
                comb[b * 164 + n * 16 + quad * 4 + r] = sacc[jj][r];
        }
    }
    __syncthreads();
    #pragma unroll
    for (int it = 0; it < 3; ++it) {
        int f = tid + BLOCK * it;
        if (f < 640) {
            int e = f * 4;
            int bb = e / 160, rem = e - bb * 160;
            float4 v = *(const float4*)(comb + bb * 164 + rem);
            *(float4*)(&p_s[((size_t)chunk * B_N + gb0 + bb) * 160 + rem]) = v;
        }
    }
}

// ---- reduce+squash; writes padded vst tiles for DMA staging ----
__global__ __launch_bounds__(BLOCK)
void reduce_squash(const float* __restrict__ p_s, float* __restrict__ vstG,
                   float* __restrict__ out, int phase)
{
    const int warp = threadIdx.x >> 6;
    const int lane = threadIdx.x & 63;
    const int g    = blockIdx.x * 4 + warp;   // 0..2559 == b*10+n
    const int q    = lane & 3;
    const int h    = lane >> 2;

    float4 s = make_float4(0.f, 0.f, 0.f, 0.f);
    #pragma unroll
    for (int m = 0; m < C_CHUNKS / 16; ++m) {   // 4
        const int cc = h + 16 * m;
        float4 v = *(const float4*)(&p_s[((size_t)cc * (B_N * N_N) + g) * D_N + q * 4]);
        s.x += v.x; s.y += v.y; s.z += v.z; s.w += v.w;
    }
    #pragma unroll
    for (int off = 4; off < 64; off <<= 1) {
        s.x += __shfl_xor(s.x, off);
        s.y += __shfl_xor(s.y, off);
        s.z += __shfl_xor(s.z, off);
        s.w += __shfl_xor(s.w, off);
    }
    float sq = s.x * s.x + s.y * s.y + s.z * s.z + s.w * s.w;
    sq += __shfl_xor(sq, 1);
    sq += __shfl_xor(sq, 2);

    const float scale = (sq / (1.f + sq)) / (sqrtf(sq) + 1e-8f);
    const float4 v = make_float4(scale * s.x, scale * s.y, scale * s.z, scale * s.w);

    if (h == 0) {
        if (phase == 2) {
            *(float4*)(&out[(size_t)g * D_N + q * 4]) = v;
        } else {
            const int bb = g / 10, n = g - bb * 10;
            float* vp = vstG + (size_t)(bb >> 4) * 2624 + (bb & 15) * 164 + n * 16 + q * 4;
            if (phase == 0) {
                *(float4*)vp = v;
            } else {
                float4 o = *(const float4*)vp;
                *(float4*)vp = make_float4(o.x + v.x, o.y + v.y, o.z + v.z, o.w + v.w);
            }
        }
    }
}

extern "C" void kernel_launch(void* const* d_in, const int* in_sizes, int n_in,
                              void* d_out, int out_size, void* d_ws, size_t ws_size,
                              hipStream_t stream)
{
    const float* x = (const float*)d_in[0];
    const float* W = (const float*)d_in[1];
    float* out  = (float*)d_out;

    float* vstG = (float*)d_ws;
    float* p_s  = vstG + VSTG_FL;
    short* Wb   = (short*)(p_s + PS_FL);
    short* xt   = Wb + WB_SH;

    conv_all<<<dim3(144 + 1024), BLOCK, 0, stream>>>(x, W, Wb, xt);

    dim3 grid(C_CHUNKS, 16);
    dim3 rgrid((B_N * N_N) / 4);

    route_pass<true><<<grid, BLOCK, 0, stream>>>(Wb, xt, vstG, p_s);
    reduce_squash<<<rgrid, BLOCK, 0, stream>>>(p_s, vstG, out, 0);
    route_pass<false><<<grid, BLOCK, 0, stream>>>(Wb, xt, vstG, p_s);
    reduce_squash<<<rgrid, BLOCK, 0, stream>>>(p_s, vstG, out, 1);
    route_pass<false><<<grid, BLOCK, 0, stream>>>(Wb, xt, vstG, p_s);
    reduce_squash<<<rgrid, BLOCK, 0, stream>>>(p_s, vstG, out, 2);
}